// Round 1
// 29201.831 us; speedup vs baseline: 1.2303x; 1.2303x over previous
//
#include <hip/hip_runtime.h>

// Problem sizes (fixed by reference)
#define BB 32
#define TT 512
#define DD 512
#define HH 512
#define LL 4
#define HB (HH * BB)           // 16384
#define NWG 192
#define TPB 256

// ws: data floats then flag/counter slots (memset to 0 by host each call)
#define STATE_FLOATS (LL * 2 * HB)              // 131072
#define GATE_FLOATS  (3 * LL * HB)              // 196608
#define DATA_FLOATS  (STATE_FLOATS + GATE_FLOATS)
#define FLAG_STRIDE  64                          // 256 B per counter slot
#define NFLAG        209                         // keep prior ws footprint
#define FLAGS_BYTES  ((unsigned long long)NFLAG * FLAG_STRIDE * 4ull)
#define WS_NEED_BYTES ((unsigned long long)DATA_FLOATS * 4ull + FLAGS_BYTES)
#define LDS_BYTES 131072       // 128 KB resident weights

// ---- self-timed dataflow counters (replace global barrier) ----
// done_A[i]: +1 per A-WG (32 ZR + 8 hU = 40/layer) per completed step.
// done_B[i]: +1 per B-WG (8/layer) per completed step.
// Dep graph per step t (0-based):
//   A(i,t): U-side needs done_B[i-1] >= 8(t+1)   (inp = s_{i-1}(t); i=0: x)
//           W-side + gate stores need done_B[i] >= 8t (prev ready + gate ack)
//   B(i,t): needs done_A[i] >= 40(t+1)           (gates of step t)
//           state stores need done_A[i+1] >= 40t (downstream read s_i(t-2))
// Publication: relaxed agent-scope atomic stores (bypass L2 -> IC; cross-XCD
// visibility proven by the prior barrier-flag mechanism), then per-thread
// s_waitcnt(0) + __syncthreads (drains all threads' stores), then atomicAdd.
// Consumption: relaxed poll, then one acquire fence (L1/L2 inv) so the
// plain vectorized loads fetch IC-fresh lines. State zero-init moved to a
// host memset so no plain-store dirty lines ever alias atomic-written data.
#define DONE_A(f, i) ((f) + (i) * FLAG_STRIDE)
#define DONE_B(f, i) ((f) + (8 + (i)) * FLAG_STRIDE)
#define SPIN_CAP (1 << 22)     // ~1.5 s worst case, then free-run (no hang)

__device__ __forceinline__ void wg_wait(int* cnt, int target, int& dead) {
    if (threadIdx.x == 0 && !dead) {
        int spins = 0;
        while (__hip_atomic_load(cnt, __ATOMIC_RELAXED,
                                 __HIP_MEMORY_SCOPE_AGENT) < target) {
            __builtin_amdgcn_s_sleep(2);
            if (++spins > SPIN_CAP) { dead = 1; break; }
        }
        // acquire: invalidate L1/L2 so subsequent plain loads see IC data
        __builtin_amdgcn_fence(__ATOMIC_ACQUIRE, "agent");
    }
    __syncthreads();
}

__device__ __forceinline__ void wg_post(int* cnt) {
    asm volatile("" ::: "memory");
    __builtin_amdgcn_s_waitcnt(0);   // this thread's stores ack'd at IC
    __syncthreads();                 // all threads drained (waitcnt+barrier)
    if (threadIdx.x == 0)
        atomicAdd(cnt, 1);           // device-scope, IC-level
}

__device__ __forceinline__ void pub_store(float* p, float v) {
    // bypass L2 -> coherence point; visible to any XCD after waitcnt ack
    __hip_atomic_store(p, v, __ATOMIC_RELAXED, __HIP_MEMORY_SCOPE_AGENT);
}

// WG roles (logical wg 0..191):
//   wg   0..127: A z/r. grp=wg>>4: i=grp>>1, g=grp&1; 32 cols; LDS = U|W
//   wg 128..159: A hU.  i=(wg-128)>>3; 64 cols; LDS = U2
//   wg 160..191: B.     i=(wg-160)>>3; 64 cols; LDS = W2
// LDS weight layouts (float4 units):
//   32-col: lds[(k*8 + c)*4]  = {M[k][c], M[k][c+8], M[k][c+16], M[k][c+24]}
//   64-col: lds[(k*16 + q)*4] = {M[k][q], M[k][q+16], M[k][q+32], M[k][q+48]}
// State/gate buffers b-major: slice[b*512 + col] -> per-lane contiguous float4.

__global__ __launch_bounds__(TPB) void gru_wave(
    const float* __restrict__ x,    // [B,T,D]
    const float* __restrict__ Wp,   // [L,3,H,H]
    const float* __restrict__ Up,   // [L,3,D,H]
    float* __restrict__ out,        // [B,T,H]
    float* __restrict__ ws)
{
    extern __shared__ float lds[];  // 32768 floats

    const int bid = blockIdx.x;
    const int wg  = (bid & 7) * 24 + (bid >> 3);   // XCD-contiguous logical id
    const int tid = threadIdx.x;
    const int b   = tid & 31;
    const int c   = tid >> 5;          // 0..7

    float* state = ws;                         // [L][2][B][H]
    float* zbuf  = state + LL * 2 * HB;        // [L][B][H]
    float* rbuf  = zbuf + LL * HB;
    float* hUbuf = rbuf + LL * HB;
    int*   flags = (int*)(ws + DATA_FLOATS);

    const bool isZR = wg < 128;
    const bool isHU = (wg >= 128) && (wg < 160);

    int iA = 0, gA = 0, col0 = 0, iB = 0, col0B = 0;
    if (isZR) { int grp = wg >> 4; iA = grp >> 1; gA = grp & 1; col0 = (wg & 15) * 32; }
    else if (isHU) { int w2 = wg - 128; iA = w2 >> 3; gA = 2; col0 = (w2 & 7) * 64; }
    else { int w3 = wg - 160; iB = w3 >> 3; col0B = (w3 & 7) * 64; }

    // ---- one-time weight staging into resident LDS ----
    if (isZR) {
        const float* Um = Up + (size_t)(iA * 3 + gA) * DD * HH + col0;
        const float* Wm = Wp + (size_t)(iA * 3 + gA) * HH * HH + col0;
        for (int u = tid; u < 4096; u += TPB) {
            int k = u >> 3, cc = u & 7;
            const float* ur = Um + (size_t)k * HH + cc;
            *(float4*)&lds[u * 4] = make_float4(ur[0], ur[8], ur[16], ur[24]);
            const float* wr = Wm + (size_t)k * HH + cc;
            *(float4*)&lds[16384 + u * 4] = make_float4(wr[0], wr[8], wr[16], wr[24]);
        }
    } else {
        const float* Mm = isHU ? (Up + (size_t)(iA * 3 + 2) * DD * HH + col0)
                               : (Wp + (size_t)(iB * 3 + 2) * HH * HH + col0B);
        for (int u = tid; u < 8192; u += TPB) {
            int k = u >> 4, q = u & 15;
            const float* mr = Mm + (size_t)k * HH + q;
            *(float4*)&lds[u * 4] = make_float4(mr[0], mr[16], mr[32], mr[48]);
        }
    }
    // No initial grid sync needed: state+flags zeroed by host memset before
    // launch; only cross-WG deps are counter-gated below.

    int dead = 0;

    if (isZR) {
        for (int t = 0; t < TT; ++t) {
            // --- U-side first: only needs inp (off the recurrence chain) ---
            if (iA > 0) wg_wait(DONE_B(flags, iA - 1), 8 * (t + 1), dead);
            const float* urow = (iA == 0)
                ? (x + ((size_t)b * TT + t) * DD)
                : (state + ((iA - 1) * 2 + (t & 1)) * HB + b * HH);
            float a0 = 0.f, a1 = 0.f, a2 = 0.f, a3 = 0.f;
            #pragma unroll 4
            for (int k4 = 0; k4 < 128; ++k4) {
                float4 xi = *(const float4*)&urow[k4 * 4];
                #pragma unroll
                for (int j = 0; j < 4; ++j) {
                    float xv = (&xi.x)[j];
                    float4 wv = *(const float4*)&lds[((k4 * 4 + j) * 8 + c) * 4];
                    a0 = fmaf(xv, wv.x, a0); a1 = fmaf(xv, wv.y, a1);
                    a2 = fmaf(xv, wv.z, a2); a3 = fmaf(xv, wv.w, a3);
                }
            }
            // --- W-side: needs prev state; also acks gate(t-1) consumed ---
            wg_wait(DONE_B(flags, iA), 8 * t, dead);
            const float* prow = state + (iA * 2 + ((t + 1) & 1)) * HB + b * HH;
            #pragma unroll 4
            for (int k4 = 0; k4 < 128; ++k4) {
                float4 pi = *(const float4*)&prow[k4 * 4];
                #pragma unroll
                for (int j = 0; j < 4; ++j) {
                    float pv = (&pi.x)[j];
                    float4 wv = *(const float4*)&lds[16384 + ((k4 * 4 + j) * 8 + c) * 4];
                    a0 = fmaf(pv, wv.x, a0); a1 = fmaf(pv, wv.y, a1);
                    a2 = fmaf(pv, wv.z, a2); a3 = fmaf(pv, wv.w, a3);
                }
            }
            float* dst = (gA == 0 ? zbuf : rbuf) + iA * HB + b * HH;
            pub_store(&dst[col0 + c     ], 1.0f / (1.0f + __expf(-a0)));
            pub_store(&dst[col0 + c +  8], 1.0f / (1.0f + __expf(-a1)));
            pub_store(&dst[col0 + c + 16], 1.0f / (1.0f + __expf(-a2)));
            pub_store(&dst[col0 + c + 24], 1.0f / (1.0f + __expf(-a3)));
            wg_post(DONE_A(flags, iA));
        }
    } else if (isHU) {
        for (int t = 0; t < TT; ++t) {
            if (iA > 0) wg_wait(DONE_B(flags, iA - 1), 8 * (t + 1), dead);
            const float* urow = (iA == 0)
                ? (x + ((size_t)b * TT + t) * DD)
                : (state + ((iA - 1) * 2 + (t & 1)) * HB + b * HH);
            float a0 = 0.f, a1 = 0.f, a2 = 0.f, a3 = 0.f;
            float a4 = 0.f, a5 = 0.f, a6 = 0.f, a7 = 0.f;
            #pragma unroll 2
            for (int k4 = 0; k4 < 128; ++k4) {
                float4 xi = *(const float4*)&urow[k4 * 4];
                #pragma unroll
                for (int j = 0; j < 4; ++j) {
                    float xv = (&xi.x)[j];
                    float4 w0 = *(const float4*)&lds[((k4 * 4 + j) * 16 + c) * 4];
                    float4 w1 = *(const float4*)&lds[((k4 * 4 + j) * 16 + c + 8) * 4];
                    a0 = fmaf(xv, w0.x, a0); a1 = fmaf(xv, w0.y, a1);
                    a2 = fmaf(xv, w0.z, a2); a3 = fmaf(xv, w0.w, a3);
                    a4 = fmaf(xv, w1.x, a4); a5 = fmaf(xv, w1.y, a5);
                    a6 = fmaf(xv, w1.z, a6); a7 = fmaf(xv, w1.w, a7);
                }
            }
            // overwrite-ack: B(i,t-1) must have consumed hU(t-1)
            wg_wait(DONE_B(flags, iA), 8 * t, dead);
            float* hu = hUbuf + iA * HB + b * HH;
            pub_store(&hu[col0 + c     ], a0);
            pub_store(&hu[col0 + c + 16], a1);
            pub_store(&hu[col0 + c + 32], a2);
            pub_store(&hu[col0 + c + 48], a3);
            pub_store(&hu[col0 + c +  8], a4);
            pub_store(&hu[col0 + c + 24], a5);
            pub_store(&hu[col0 + c + 40], a6);
            pub_store(&hu[col0 + c + 56], a7);
            wg_post(DONE_A(flags, iA));
        }
    } else {
        for (int t = 0; t < TT; ++t) {
            // gates of step t ready (implies prev-state B(i,t-1) done too,
            // since A(i,t) waited on done_B[i] >= 8t)
            wg_wait(DONE_A(flags, iB), 40 * (t + 1), dead);
            const float* prow = state + (iB * 2 + ((t + 1) & 1)) * HB + b * HH;
            const float* rrow = rbuf + iB * HB + b * HH;
            float a0 = 0.f, a1 = 0.f, a2 = 0.f, a3 = 0.f;
            float a4 = 0.f, a5 = 0.f, a6 = 0.f, a7 = 0.f;
            #pragma unroll 2
            for (int k4 = 0; k4 < 128; ++k4) {
                float4 ri = *(const float4*)&rrow[k4 * 4];
                float4 pi = *(const float4*)&prow[k4 * 4];
                #pragma unroll
                for (int j = 0; j < 4; ++j) {
                    float rp = (&ri.x)[j] * (&pi.x)[j];
                    float4 w0 = *(const float4*)&lds[((k4 * 4 + j) * 16 + c) * 4];
                    float4 w1 = *(const float4*)&lds[((k4 * 4 + j) * 16 + c + 8) * 4];
                    a0 = fmaf(rp, w0.x, a0); a1 = fmaf(rp, w0.y, a1);
                    a2 = fmaf(rp, w0.z, a2); a3 = fmaf(rp, w0.w, a3);
                    a4 = fmaf(rp, w1.x, a4); a5 = fmaf(rp, w1.y, a5);
                    a6 = fmaf(rp, w1.z, a6); a7 = fmaf(rp, w1.w, a7);
                }
            }
            // state(t-2) slot overwrite-ack: downstream A(i+1,t-1) done
            if (iB < 3) wg_wait(DONE_A(flags, iB + 1), 40 * t, dead);
            float* stNew = state + (iB * 2 + (t & 1)) * HB + b * HH;
            const float* hu = hUbuf + iB * HB + b * HH;
            const float* zz = zbuf + iB * HB + b * HH;
            float accv[8] = {a0, a1, a2, a3, a4, a5, a6, a7};
            const int coff[8] = {0, 16, 32, 48, 8, 24, 40, 56};
            #pragma unroll
            for (int j = 0; j < 8; ++j) {
                const int col = col0B + c + coff[j];
                float a2v = accv[j] + hu[col];
                float h   = tanhf(a2v);
                float zg  = zz[col];
                float pv  = prow[col];
                float s   = zg * (pv - h) + h;      // (1-z)*h + z*prev
                pub_store(&stNew[col], s);
                if (iB == LL - 1)
                    out[((size_t)b * TT + t) * HH + col] = s;  // plain; flushed at kernel end
            }
            wg_post(DONE_B(flags, iB));
        }
    }
}

extern "C" void kernel_launch(void* const* d_in, const int* in_sizes, int n_in,
                              void* d_out, int out_size, void* d_ws, size_t ws_size,
                              hipStream_t stream) {
    const float* x  = (const float*)d_in[0];  // [32,512,512]
    const float* Wp = (const float*)d_in[1];  // [4,3,512,512]
    const float* Up = (const float*)d_in[2];  // [4,3,512,512]
    float* out = (float*)d_out;
    float* ws  = (float*)d_ws;

    // Sentinel 1: workspace too small -> absmax ~8.5e37
    if (ws_size < WS_NEED_BYTES) {
        hipMemsetAsync(d_out, 0x7e, (size_t)out_size * sizeof(float), stream);
        return;
    }

    // Host-side zero of state (t=0 prev) and counters each call.
    // Critical: state must never be dirtied by plain in-kernel stores, since
    // the kernel publishes state via L2-bypassing atomic stores.
    hipMemsetAsync(ws, 0, (size_t)STATE_FLOATS * sizeof(float), stream);
    hipMemsetAsync(ws + DATA_FLOATS, 0, FLAGS_BYTES, stream);

    hipLaunchKernelGGL(gru_wave, dim3(NWG), dim3(TPB), LDS_BYTES, stream,
                       x, Wp, Up, out, ws);
    // Sentinel 2: launch rejected -> absmax ~3.4e38
    hipError_t err = hipGetLastError();
    if (err != hipSuccess)
        hipMemsetAsync(d_out, 0x7f, (size_t)out_size * sizeof(float), stream);
}